// Round 3
// baseline (427.611 us; speedup 1.0000x reference)
//
#include <hip/hip_runtime.h>

#define DF 64
#define BSH 8              // bucket = dst >> 8  (256 dst per bucket)
#define BW  256

typedef unsigned short u16;
typedef unsigned int u32;
typedef __attribute__((ext_vector_type(8))) short short8;
typedef __attribute__((ext_vector_type(4))) float f32x4;

__device__ __forceinline__ float bf2f(u16 u) { return __uint_as_float(((u32)u) << 16); }
__device__ __forceinline__ u16 f2bf(float f) {
  u32 v = __float_as_uint(f);
  return (u16)((v + 0x7FFFu + ((v >> 16) & 1u)) >> 16);
}

// ============== bucket-sort CSR build (atomic-free globals) ==============

__global__ __launch_bounds__(256) void prehist(const int* __restrict__ ei,
                                               int* __restrict__ gh, int E, int NB) {
  __shared__ int lh[512];
  for (int t = threadIdx.x; t < NB; t += 256) lh[t] = 0;
  __syncthreads();
  int e0 = blockIdx.x * 1024;
#pragma unroll
  for (int j = 0; j < 4; j++) {
    int e = e0 + j * 256 + threadIdx.x;
    if (e < E) atomicAdd(&lh[ei[E + e] >> BSH], 1);
  }
  __syncthreads();
  for (int t = threadIdx.x; t < NB; t += 256)
    gh[(size_t)blockIdx.x * NB + t] = lh[t];
}

__global__ __launch_bounds__(256) void scanA(int* __restrict__ gh, int* __restrict__ btot,
                                             int nblk, int NB) {
  int c = blockIdx.x;
  __shared__ int sc[256];
  int carry = 0;
  for (int b0 = 0; b0 < nblk; b0 += 256) {
    int b = b0 + threadIdx.x;
    int orig = (b < nblk) ? gh[(size_t)b * NB + c] : 0;
    int v = orig;
    sc[threadIdx.x] = v;
    __syncthreads();
    for (int off = 1; off < 256; off <<= 1) {
      int o = threadIdx.x >= off ? sc[threadIdx.x - off] : 0;
      __syncthreads();
      v += o;
      sc[threadIdx.x] = v;
      __syncthreads();
    }
    int ctot = sc[255];
    if (b < nblk) gh[(size_t)b * NB + c] = carry + v - orig;
    carry += ctot;
    __syncthreads();
  }
  if (threadIdx.x == 0) btot[c] = carry;
}

__global__ __launch_bounds__(256) void scanB(const int* __restrict__ btot,
                                             int* __restrict__ bstart,
                                             int* __restrict__ rowptr, int NB, int n, int E) {
  __shared__ int sc[256];
  int base = threadIdx.x * 4;
  int c[4], s = 0;
#pragma unroll
  for (int j = 0; j < 4; j++) {
    int idx = base + j;
    c[j] = idx < NB ? btot[idx] : 0;
    s += c[j];
  }
  int v = s;
  sc[threadIdx.x] = v;
  __syncthreads();
  for (int off = 1; off < 256; off <<= 1) {
    int o = threadIdx.x >= off ? sc[threadIdx.x - off] : 0;
    __syncthreads();
    v += o;
    sc[threadIdx.x] = v;
    __syncthreads();
  }
  int run = v - s;
#pragma unroll
  for (int j = 0; j < 4; j++) {
    int idx = base + j;
    if (idx <= NB) bstart[idx] = run;
    run += c[j];
  }
  if (threadIdx.x == 0) rowptr[n] = E;   // sentinel (pass2 rewrites same value if n%256!=0)
}

// bin edges into dst-buckets; 8B records {dl | src<<8, w_fp32}
__global__ __launch_bounds__(256) void pass1(const int* __restrict__ ei,
                                             const float* __restrict__ w,
                                             const int* __restrict__ gh,
                                             const int* __restrict__ bstart,
                                             int2* __restrict__ pk1, int E, int NB) {
  __shared__ int lh[512];
  __shared__ int lbase[512];
  for (int t = threadIdx.x; t < NB; t += 256) lh[t] = 0;
  __syncthreads();
  int e0 = blockIdx.x * 1024;
  int s[4], d[4], r[4];
  float wv[4];
#pragma unroll
  for (int j = 0; j < 4; j++) {
    int e = e0 + j * 256 + threadIdx.x;
    if (e < E) {
      s[j] = ei[e];
      d[j] = ei[E + e];
      wv[j] = w[e];
      r[j] = atomicAdd(&lh[d[j] >> BSH], 1);
    }
  }
  __syncthreads();
  for (int t = threadIdx.x; t < NB; t += 256)
    lbase[t] = bstart[t] + gh[(size_t)blockIdx.x * NB + t];
  __syncthreads();
#pragma unroll
  for (int j = 0; j < 4; j++) {
    int e = e0 + j * 256 + threadIdx.x;
    if (e < E)
      pk1[lbase[d[j] >> BSH] + r[j]] =
          make_int2((d[j] & 255) | (s[j] << 8), __float_as_int(wv[j]));
  }
}

// per-bucket counting sort (LDS) -> pk2 {src | dl<<17, w_fp32}; emit dinv + per-node rowptr
__global__ __launch_bounds__(256) void pass2(const int2* __restrict__ pk1,
                                             const int* __restrict__ bstart,
                                             int2* __restrict__ pk2,
                                             float* __restrict__ dinv,
                                             int* __restrict__ rowptr, int n) {
  int c = blockIdx.x;
  int dbase = c << BSH;
  __shared__ int h[BW];
  __shared__ float dg[BW];
  __shared__ int sc[BW];
  __shared__ int cur[BW];
  h[threadIdx.x] = 0;
  dg[threadIdx.x] = 0.f;
  __syncthreads();
  int e0 = bstart[c], e1 = bstart[c + 1];
  for (int e = e0 + threadIdx.x; e < e1; e += 256) {
    int2 p = pk1[e];
    int dl = p.x & 255;
    atomicAdd(&h[dl], 1);
    atomicAdd(&dg[dl], __int_as_float(p.y));
  }
  __syncthreads();
  int own = h[threadIdx.x];
  int v = own;
  sc[threadIdx.x] = v;
  __syncthreads();
  for (int off = 1; off < 256; off <<= 1) {
    int o = threadIdx.x >= off ? sc[threadIdx.x - off] : 0;
    __syncthreads();
    v += o;
    sc[threadIdx.x] = v;
    __syncthreads();
  }
  int start = e0 + v - own;
  cur[threadIdx.x] = start;
  int i = dbase + threadIdx.x;
  if (i < n) dinv[i] = rsqrtf(dg[threadIdx.x] + 1.0f);   // self-loop +1
  if (i <= n) rowptr[i] = start;                          // per-node CSR pointer
  __syncthreads();
  for (int e = e0 + threadIdx.x; e < e1; e += 256) {
    int2 p = pk1[e];
    int dl = p.x & 255;
    int slot = atomicAdd(&cur[dl], 1);
    pk2[slot] = make_int2((p.x >> 8) | (dl << 17), p.y);
  }
}

// ================= compute =================

// B fragment for MFMA 16x16x32: B[k = k0+j][col], bf16-RNE from fp32 W
__device__ __forceinline__ short8 bfrag(const float* __restrict__ W, int k0, int col) {
  short8 b;
#pragma unroll
  for (int j = 0; j < 8; j++) b[j] = (short)f2bf(W[(k0 + j) * DF + col]);
  return b;
}

// MFMA GEMM: xl' = bf16( (bf16(A) @ bf16(W)) * dinv_row )   (src-side dinv folded in)
__global__ __launch_bounds__(256) void gemm_init(const float* __restrict__ A,
                                                 const float* __restrict__ W,
                                                 const float* __restrict__ dinv,
                                                 u16* __restrict__ xl, int n, int tiles) {
  int lane = threadIdx.x & 63;
  int m = lane & 15, quad = lane >> 4;
  int wid = blockIdx.x * 4 + (threadIdx.x >> 6);
  int nw = gridDim.x * 4;
  short8 B0[4], B1[4];
#pragma unroll
  for (int ft = 0; ft < 4; ft++) {
    B0[ft] = bfrag(W, quad * 8, ft * 16 + m);
    B1[ft] = bfrag(W, 32 + quad * 8, ft * 16 + m);
  }
  for (int t = wid; t < tiles; t += nw) {
    int row0 = t * 16;
    int r = row0 + m;
    if (r >= n) r = n - 1;
    const float* ap = A + (size_t)r * DF + quad * 8;
    float4 u0 = *(const float4*)ap;
    float4 u1 = *(const float4*)(ap + 4);
    float4 u2 = *(const float4*)(ap + 32);
    float4 u3 = *(const float4*)(ap + 36);
    short8 a0, a1;
    a0[0]=(short)f2bf(u0.x); a0[1]=(short)f2bf(u0.y); a0[2]=(short)f2bf(u0.z); a0[3]=(short)f2bf(u0.w);
    a0[4]=(short)f2bf(u1.x); a0[5]=(short)f2bf(u1.y); a0[6]=(short)f2bf(u1.z); a0[7]=(short)f2bf(u1.w);
    a1[0]=(short)f2bf(u2.x); a1[1]=(short)f2bf(u2.y); a1[2]=(short)f2bf(u2.z); a1[3]=(short)f2bf(u2.w);
    a1[4]=(short)f2bf(u3.x); a1[5]=(short)f2bf(u3.y); a1[6]=(short)f2bf(u3.z); a1[7]=(short)f2bf(u3.w);
    f32x4 c[4];
#pragma unroll
    for (int ft = 0; ft < 4; ft++) c[ft] = (f32x4){0.f, 0.f, 0.f, 0.f};
#pragma unroll
    for (int ft = 0; ft < 4; ft++) {
      c[ft] = __builtin_amdgcn_mfma_f32_16x16x32_bf16(a0, B0[ft], c[ft], 0, 0, 0);
      c[ft] = __builtin_amdgcn_mfma_f32_16x16x32_bf16(a1, B1[ft], c[ft], 0, 0, 0);
    }
    float dd[4];
#pragma unroll
    for (int reg = 0; reg < 4; reg++) {
      int r2 = row0 + quad * 4 + reg;
      dd[reg] = (r2 < n) ? dinv[r2] : 0.f;
    }
#pragma unroll
    for (int ft = 0; ft < 4; ft++)
#pragma unroll
      for (int reg = 0; reg < 4; reg++) {
        int r2 = row0 + quad * 4 + reg;
        if (r2 < n)
          xl[(size_t)r2 * DF + ft * 16 + m] = f2bf(c[ft][reg] * dd[reg]);
      }
  }
}

// MFMA GEMM with BN+PReLU fused into A-load; same dinv-folded bf16 output
__global__ __launch_bounds__(256) void gemm_bn_init(const float* __restrict__ accin,
                                                    const float* __restrict__ stats,
                                                    const float* __restrict__ alpha_p,
                                                    const float* __restrict__ W,
                                                    const float* __restrict__ dinv,
                                                    u16* __restrict__ xl, int n, int tiles) {
  int lane = threadIdx.x & 63;
  int m = lane & 15, quad = lane >> 4;
  int wid = blockIdx.x * 4 + (threadIdx.x >> 6);
  int nw = gridDim.x * 4;
  short8 B0[4], B1[4];
#pragma unroll
  for (int ft = 0; ft < 4; ft++) {
    B0[ft] = bfrag(W, quad * 8, ft * 16 + m);
    B1[ft] = bfrag(W, 32 + quad * 8, ft * 16 + m);
  }
  float s0[8], t0[8], s1[8], t1[8];
#pragma unroll
  for (int j = 0; j < 8; j++) {
    s0[j] = stats[128 + quad * 8 + j];
    t0[j] = stats[192 + quad * 8 + j];
    s1[j] = stats[128 + 32 + quad * 8 + j];
    t1[j] = stats[192 + 32 + quad * 8 + j];
  }
  float al = alpha_p[0];
  for (int t = wid; t < tiles; t += nw) {
    int row0 = t * 16;
    int r = row0 + m;
    if (r >= n) r = n - 1;
    const float* ap = accin + (size_t)r * DF + quad * 8;
    float h0[8], h1[8];
#pragma unroll
    for (int j = 0; j < 8; j++) { h0[j] = ap[j]; h1[j] = ap[32 + j]; }
    short8 a0, a1;
#pragma unroll
    for (int j = 0; j < 8; j++) {
      float y0 = h0[j] * s0[j] + t0[j];
      y0 = (y0 >= 0.f) ? y0 : al * y0;
      a0[j] = (short)f2bf(y0);
      float y1 = h1[j] * s1[j] + t1[j];
      y1 = (y1 >= 0.f) ? y1 : al * y1;
      a1[j] = (short)f2bf(y1);
    }
    f32x4 c[4];
#pragma unroll
    for (int ft = 0; ft < 4; ft++) c[ft] = (f32x4){0.f, 0.f, 0.f, 0.f};
#pragma unroll
    for (int ft = 0; ft < 4; ft++) {
      c[ft] = __builtin_amdgcn_mfma_f32_16x16x32_bf16(a0, B0[ft], c[ft], 0, 0, 0);
      c[ft] = __builtin_amdgcn_mfma_f32_16x16x32_bf16(a1, B1[ft], c[ft], 0, 0, 0);
    }
    float dd[4];
#pragma unroll
    for (int reg = 0; reg < 4; reg++) {
      int r2 = row0 + quad * 4 + reg;
      dd[reg] = (r2 < n) ? dinv[r2] : 0.f;
    }
#pragma unroll
    for (int ft = 0; ft < 4; ft++)
#pragma unroll
      for (int reg = 0; reg < 4; reg++) {
        int r2 = row0 + quad * 4 + reg;
        if (r2 < n)
          xl[(size_t)r2 * DF + ft * 16 + m] = f2bf(c[ft][reg] * dd[reg]);
      }
  }
}

// owner-computes segmented aggregation with FORCED 3-batch-deep gather pipeline.
// Gathers are inline-asm global_load_ushort (saddr = wave-uniform src row, voffset =
// lane*2) -> opaque to regalloc, cannot be collapsed. Counted s_waitcnt vmcnt(N).
// Loop body has ZERO compiler-tracked VMEM: acc stores deferred via shift register
// (exactly 8 flushes/wave), row state prefetched, bias pinned before the pipeline.
__global__ __launch_bounds__(256) void edge_agg4(const int2* __restrict__ pk,
                                                 const int* __restrict__ rowptr,
                                                 const u16* __restrict__ xl,
                                                 const float* __restrict__ dinv,
                                                 const float* __restrict__ bias,
                                                 float* __restrict__ acc,
                                                 float* __restrict__ statp, int n) {
  int lane = threadIdx.x & 63;
  int wsub = threadIdx.x >> 6;
  int r0 = (blockIdx.x * 4 + wsub) * 8;
  int ru = __builtin_amdgcn_readfirstlane(r0);
  float bl = bias[lane];
  asm volatile("" :: "v"(bl));   // pin bl resident BEFORE untracked asm loads
  float ssum = 0.f, ssq = 0.f;
  u32 voff = (u32)lane * 2u;
  unsigned long long xlB = (unsigned long long)(uintptr_t)xl;

#define GLD(dst, sbase) \
  asm volatile("global_load_ushort %0, %1, %2" : "=v"(dst) : "v"(voff), "s"(sbase))

#define WAIT_REM(rem_) do {                                          \
    int _r = (rem_);                                                 \
    if (_r >= 2)      asm volatile("s_waitcnt vmcnt(32)" ::: "memory"); \
    else if (_r == 1) asm volatile("s_waitcnt vmcnt(16)" ::: "memory"); \
    else              asm volatile("s_waitcnt vmcnt(0)"  ::: "memory"); \
    __builtin_amdgcn_sched_barrier(0);                               \
  } while (0)

  if (ru < n) {
    if (ru + 8 <= n) {
      // ---------------- fast path: full 8-row group ----------------
      int eb0 = __builtin_amdgcn_readfirstlane(rowptr[ru]);
      int cnt = __builtin_amdgcn_readfirstlane(rowptr[ru + 8]) - eb0;
      const int2* __restrict__ pw = pk + eb0;
      int bc = (cnt + 15) >> 4;
      int cmax = (cnt > 0) ? cnt - 1 : 0;
      // scalar row state (SMEM, lgkm-tracked - safe)
      float d0 = dinv[ru],     d1 = dinv[ru + 1], d2 = dinv[ru + 2], d3 = dinv[ru + 3];
      float d4 = dinv[ru + 4], d5 = dinv[ru + 5], d6 = dinv[ru + 6], d7 = dinv[ru + 7];
      // self-row prefetch via untracked asm loads
      u32 sx[8];
#pragma unroll
      for (int k = 0; k < 8; k++) {
        unsigned long long sb = xlB + ((unsigned long long)(u32)(ru + k) << 7);
        GLD(sx[k], sb);
      }
      u32 xA[16], xB[16], xC[16];

#define STAGE(b_, XR_) do {                                           \
      int eb_ = (b_) * 16;                                            \
      _Pragma("unroll")                                               \
      for (int j = 0; j < 16; j++) {                                  \
        int e_ = eb_ + j;                                             \
        int ec_ = e_ < cnt ? e_ : cmax;                               \
        int2 p_ = pw[ec_];                                            \
        unsigned long long sb_ =                                      \
            xlB + ((unsigned long long)(u32)(p_.x & 0x1FFFF) << 7);   \
        GLD(XR_[j], sb_);                                             \
      }                                                               \
    } while (0)

#define FLUSH() do {                                                  \
      float val_ = fmaf(a, d0, bl);                                   \
      ssum += val_; ssq = fmaf(val_, val_, ssq);                      \
      o7 = o6; o6 = o5; o5 = o4; o4 = o3; o3 = o2; o2 = o1; o1 = o0; o0 = val_; \
      a = s1; s1 = s2; s2 = s3; s3 = s4; s4 = s5; s5 = s6; s6 = s7;   \
      d0 = d1; d1 = d2; d2 = d3; d3 = d4; d4 = d5; d5 = d6; d6 = d7;  \
      curdl++; f++;                                                   \
    } while (0)

#define CONSUME(b_, XR_) do {                                         \
      int eb_ = (b_) * 16;                                            \
      _Pragma("unroll")                                               \
      for (int j = 0; j < 16; j++) {                                  \
        int e_ = eb_ + j;                                             \
        int ec_ = e_ < cnt ? e_ : cmax;                               \
        int2 p_ = pw[ec_];                                            \
        int dl_ = (p_.x >> 17) & 255;                                 \
        float wv_ = (e_ < cnt) ? __int_as_float(p_.y) : 0.f;          \
        float xv_ = __uint_as_float(XR_[j] << 16);                    \
        while (dl_ != curdl) FLUSH();                                 \
        a = fmaf(wv_, xv_, a);                                        \
      }                                                               \
    } while (0)

      if (cnt > 0) STAGE(0, xA);
      if (bc > 1) STAGE(1, xB);
      WAIT_REM(bc);                      // forces self-row loads complete
      // convert self rows (now valid)
      float a  = __uint_as_float(sx[0] << 16);
      float s1 = __uint_as_float(sx[1] << 16), s2 = __uint_as_float(sx[2] << 16);
      float s3 = __uint_as_float(sx[3] << 16), s4 = __uint_as_float(sx[4] << 16);
      float s5 = __uint_as_float(sx[5] << 16), s6 = __uint_as_float(sx[6] << 16);
      float s7 = __uint_as_float(sx[7] << 16);
      float o0 = 0.f, o1 = 0.f, o2 = 0.f, o3 = 0.f, o4 = 0.f, o5 = 0.f, o6 = 0.f, o7 = 0.f;
      int curdl = ru & 255;
      int f = 0;
      int b = 0;
      while (b < bc) {
        if (b + 2 < bc) STAGE(b + 2, xC);
        WAIT_REM(bc - 1 - b);
        CONSUME(b, xA);
        b++;
        if (b >= bc) break;
        if (b + 2 < bc) STAGE(b + 2, xA);
        WAIT_REM(bc - 1 - b);
        CONSUME(b, xB);
        b++;
        if (b >= bc) break;
        if (b + 2 < bc) STAGE(b + 2, xB);
        WAIT_REM(bc - 1 - b);
        CONSUME(b, xC);
        b++;
      }
      while (f < 8) FLUSH();
      // deferred coalesced stores (o0 = last row ... o7 = first row)
      size_t rb = ((size_t)ru << 6) | (size_t)lane;
      acc[rb]          = o7;
      acc[rb + 64]     = o6;
      acc[rb + 128]    = o5;
      acc[rb + 192]    = o4;
      acc[rb + 256]    = o3;
      acc[rb + 320]    = o2;
      acc[rb + 384]    = o1;
      acc[rb + 448]    = o0;
#undef STAGE
#undef FLUSH
#undef CONSUME
    } else {
      // ---------------- tail path (rare): simple per-row walk ----------------
      int rend = n;
      for (int row = ru; row < rend; row++) {
        float aa = bf2f(xl[((size_t)row << 6) | lane]);
        int e0 = __builtin_amdgcn_readfirstlane(rowptr[row]);
        int e1 = __builtin_amdgcn_readfirstlane(rowptr[row + 1]);
        for (int e = e0; e < e1; e++) {
          int2 p = pk[e];
          float xv = bf2f(xl[((size_t)(p.x & 0x1FFFF) << 6) | lane]);
          aa = fmaf(__int_as_float(p.y), xv, aa);
        }
        float val = fmaf(aa, dinv[row], bl);
        acc[((size_t)row << 6) | lane] = val;
        ssum += val;
        ssq = fmaf(val, val, ssq);
      }
    }
  }
#undef GLD
#undef WAIT_REM
  __shared__ float ls[4][DF], lss[4][DF];
  ls[wsub][lane] = ssum;
  lss[wsub][lane] = ssq;
  __syncthreads();
  if (threadIdx.x < DF) {
    int fi = threadIdx.x;
    float t1 = ls[0][fi] + ls[1][fi] + ls[2][fi] + ls[3][fi];
    float t2 = lss[0][fi] + lss[1][fi] + lss[2][fi] + lss[3][fi];
    int slot = (blockIdx.x & 63) * 128;   // 64-way spread kills same-line contention
    unsafeAtomicAdd(&statp[slot + fi], t1);
    unsafeAtomicAdd(&statp[slot + DF + fi], t2);
  }
}

__global__ void finalize_stats(const float* __restrict__ statp, float* __restrict__ stats,
                               const float* __restrict__ gamma,
                               const float* __restrict__ beta, int n) {
  int f = threadIdx.x;
  if (f >= DF) return;
  float s = 0.f, ss = 0.f;
#pragma unroll 4
  for (int c = 0; c < 64; c++) {
    s += statp[c * 128 + f];
    ss += statp[c * 128 + DF + f];
  }
  float mean = s / n;
  float var = ss / n - mean * mean;
  float rstd = rsqrtf(var + 1e-5f);
  float sc = gamma[f] * rstd;
  stats[128 + f] = sc;
  stats[192 + f] = beta[f] - mean * sc;
}

__global__ void bnapply(const float* __restrict__ acc, const float* __restrict__ stats,
                        const float* __restrict__ alpha_p, float* __restrict__ outb, int n) {
  int i = blockIdx.x * 4 + (threadIdx.x >> 6);
  if (i >= n) return;
  int f = threadIdx.x & 63;
  float y = acc[(size_t)i * DF + f] * stats[128 + f] + stats[192 + f];
  float a = alpha_p[0];
  y = (y >= 0.f) ? y : a * y;
  outb[(size_t)i * DF + f] = y;
}

extern "C" void kernel_launch(void* const* d_in, const int* in_sizes, int n_in,
                              void* d_out, int out_size, void* d_ws, size_t ws_size,
                              hipStream_t stream) {
  const float* x  = (const float*)d_in[0];
  const int* ei   = (const int*)d_in[1];
  const float* w  = (const float*)d_in[2];
  const float* W1 = (const float*)d_in[3];
  const float* b1 = (const float*)d_in[4];
  const float* g1 = (const float*)d_in[5];
  const float* be1= (const float*)d_in[6];
  const float* al1= (const float*)d_in[7];
  const float* W2 = (const float*)d_in[8];
  const float* b2 = (const float*)d_in[9];
  const float* g2 = (const float*)d_in[10];
  const float* be2= (const float*)d_in[11];
  const float* al2= (const float*)d_in[12];
  float* out = (float*)d_out;

  const int n = in_sizes[0] / DF;
  const int E = in_sizes[2];
  const size_t na = ((size_t)n + 255) & ~(size_t)255;
  const int NB = (n + BW - 1) >> BSH;
  const int nblk1 = (E + 1023) / 1024;
  const size_t ghsz = (((size_t)nblk1 * NB) + 3) & ~(size_t)3;
  const int tiles = (n + 15) / 16;

  // ---- workspace layout (4-byte units; int2 arrays 8B-aligned) ----
  float* wsf = (float*)d_ws;
  float* stats1 = wsf;                          // 256
  float* stats2 = stats1 + 256;                 // 256
  float* statp1 = stats2 + 256;                 // 8192 (64 spread copies x 128)
  float* statp2 = statp1 + 8192;                // 8192
  int*   btot   = (int*)(statp2 + 8192);        // 512
  int*   bstart = btot + 512;                   // 512 (NB+1 used)
  int*   rowptr = bstart + 512;                 // na + 4 (n+1 used)
  float* dinv   = (float*)(rowptr + na + 4);    // na
  int*   gh     = (int*)(dinv + na);            // ghsz
  int2*  pk2    = (int2*)(gh + ghsz);           // E+64 records (8B each)
  int*   U      = (int*)(pk2 + (E + 64));       // overlay: pk1 (2E) | XL16+ACC
  int2*  pk1    = (int2*)U;
  u16*   XL16   = (u16*)U;                      // na*64 bf16 (after pass2)
  float* ACC    = (float*)(U + na * 32);        // na*64 fp32

  const int nb_nodes = (n + 3) / 4;
  const int nb_gemm  = 512;
  const int nb_agg   = (n + 31) / 32;

  hipMemsetAsync(stats1, 0, (512 + 16384) * sizeof(float), stream);

  // ---- CSR build (bucket sort, 8B records, per-node rowptr) ----
  prehist<<<nblk1, 256, 0, stream>>>(ei, gh, E, NB);
  scanA<<<NB, 256, 0, stream>>>(gh, btot, nblk1, NB);
  scanB<<<1, 256, 0, stream>>>(btot, bstart, rowptr, NB, n, E);
  pass1<<<nblk1, 256, 0, stream>>>(ei, w, gh, bstart, pk1, E, NB);
  pass2<<<NB, 256, 0, stream>>>(pk1, bstart, pk2, dinv, rowptr, n);

  // ---- layer 1 ----
  gemm_init<<<nb_gemm, 256, 0, stream>>>(x, W1, dinv, XL16, n, tiles);
  edge_agg4<<<nb_agg, 256, 0, stream>>>(pk2, rowptr, XL16, dinv, b1, ACC, statp1, n);
  finalize_stats<<<1, 64, 0, stream>>>(statp1, stats1, g1, be1, n);

  // ---- layer 2 ----
  gemm_bn_init<<<nb_gemm, 256, 0, stream>>>(ACC, stats1, al1, W2, dinv, XL16, n, tiles);
  edge_agg4<<<nb_agg, 256, 0, stream>>>(pk2, rowptr, XL16, dinv, b2, ACC, statp2, n);
  finalize_stats<<<1, 64, 0, stream>>>(statp2, stats2, g2, be2, n);
  bnapply<<<nb_nodes, 256, 0, stream>>>(ACC, stats2, al2, out, n);
}

// Round 4
// 331.121 us; speedup vs baseline: 1.2914x; 1.2914x over previous
//
#include <hip/hip_runtime.h>

#define DF 64
#define BSH 8              // bucket = dst >> 8  (256 dst per bucket)
#define BW  256
#define PADCAP 768         // per-bucket extra pk2 capacity: 256 dst * 3 pad max

typedef unsigned short u16;
typedef unsigned int u32;
typedef __attribute__((ext_vector_type(8))) short short8;
typedef __attribute__((ext_vector_type(4))) float f32x4;

__device__ __forceinline__ float bf2f(u16 u) { return __uint_as_float(((u32)u) << 16); }
__device__ __forceinline__ u16 f2bf(float f) {
  u32 v = __float_as_uint(f);
  return (u16)((v + 0x7FFFu + ((v >> 16) & 1u)) >> 16);
}

// ============== bucket-sort CSR build (atomic-free globals) ==============

__global__ __launch_bounds__(256) void prehist(const int* __restrict__ ei,
                                               int* __restrict__ gh, int E, int NB) {
  __shared__ int lh[512];
  for (int t = threadIdx.x; t < NB; t += 256) lh[t] = 0;
  __syncthreads();
  int e0 = blockIdx.x * 1024;
#pragma unroll
  for (int j = 0; j < 4; j++) {
    int e = e0 + j * 256 + threadIdx.x;
    if (e < E) atomicAdd(&lh[ei[E + e] >> BSH], 1);
  }
  __syncthreads();
  for (int t = threadIdx.x; t < NB; t += 256)
    gh[(size_t)blockIdx.x * NB + t] = lh[t];
}

__global__ __launch_bounds__(256) void scanA(int* __restrict__ gh, int* __restrict__ btot,
                                             int nblk, int NB) {
  int c = blockIdx.x;
  __shared__ int sc[256];
  int carry = 0;
  for (int b0 = 0; b0 < nblk; b0 += 256) {
    int b = b0 + threadIdx.x;
    int orig = (b < nblk) ? gh[(size_t)b * NB + c] : 0;
    int v = orig;
    sc[threadIdx.x] = v;
    __syncthreads();
    for (int off = 1; off < 256; off <<= 1) {
      int o = threadIdx.x >= off ? sc[threadIdx.x - off] : 0;
      __syncthreads();
      v += o;
      sc[threadIdx.x] = v;
      __syncthreads();
    }
    int ctot = sc[255];
    if (b < nblk) gh[(size_t)b * NB + c] = carry + v - orig;
    carry += ctot;
    __syncthreads();
  }
  if (threadIdx.x == 0) btot[c] = carry;
}

__global__ __launch_bounds__(256) void scanB(const int* __restrict__ btot,
                                             int* __restrict__ bstart,
                                             int* __restrict__ rowptr, int NB, int n, int E) {
  __shared__ int sc[256];
  int base = threadIdx.x * 4;
  int c[4], s = 0;
#pragma unroll
  for (int j = 0; j < 4; j++) {
    int idx = base + j;
    c[j] = idx < NB ? btot[idx] : 0;
    s += c[j];
  }
  int v = s;
  sc[threadIdx.x] = v;
  __syncthreads();
  for (int off = 1; off < 256; off <<= 1) {
    int o = threadIdx.x >= off ? sc[threadIdx.x - off] : 0;
    __syncthreads();
    v += o;
    sc[threadIdx.x] = v;
    __syncthreads();
  }
  int run = v - s;
#pragma unroll
  for (int j = 0; j < 4; j++) {
    int idx = base + j;
    if (idx <= NB) bstart[idx] = run;
    run += c[j];
  }
  if (threadIdx.x == 0) rowptr[n] = E;   // backup sentinel (pass2 overwrites when it covers i==n)
}

// bin edges into dst-buckets; 8B records {dl | src<<8, w_fp32}
__global__ __launch_bounds__(256) void pass1(const int* __restrict__ ei,
                                             const float* __restrict__ w,
                                             const int* __restrict__ gh,
                                             const int* __restrict__ bstart,
                                             int2* __restrict__ pk1, int E, int NB) {
  __shared__ int lh[512];
  __shared__ int lbase[512];
  for (int t = threadIdx.x; t < NB; t += 256) lh[t] = 0;
  __syncthreads();
  int e0 = blockIdx.x * 1024;
  int s[4], d[4], r[4];
  float wv[4];
#pragma unroll
  for (int j = 0; j < 4; j++) {
    int e = e0 + j * 256 + threadIdx.x;
    if (e < E) {
      s[j] = ei[e];
      d[j] = ei[E + e];
      wv[j] = w[e];
      r[j] = atomicAdd(&lh[d[j] >> BSH], 1);
    }
  }
  __syncthreads();
  for (int t = threadIdx.x; t < NB; t += 256)
    lbase[t] = bstart[t] + gh[(size_t)blockIdx.x * NB + t];
  __syncthreads();
#pragma unroll
  for (int j = 0; j < 4; j++) {
    int e = e0 + j * 256 + threadIdx.x;
    if (e < E)
      pk1[lbase[d[j] >> BSH] + r[j]] =
          make_int2((d[j] & 255) | (s[j] << 8), __float_as_int(wv[j]));
  }
}

// per-bucket counting sort (LDS) -> pk2 {src | dl<<17, w_fp32}; per-row counts padded
// to a multiple of 4 with {src=self, w=0} records so 4-edge steps never straddle rows.
// Emits dinv, PADDED per-node rowptr, and per-bucket padded end (bendp).
__global__ __launch_bounds__(256) void pass2(const int2* __restrict__ pk1,
                                             const int* __restrict__ bstart,
                                             int2* __restrict__ pk2,
                                             float* __restrict__ dinv,
                                             int* __restrict__ rowptr,
                                             int* __restrict__ bendp, int n) {
  int c = blockIdx.x;
  int dbase = c << BSH;
  __shared__ int h[BW];
  __shared__ float dg[BW];
  __shared__ int sc[BW];
  __shared__ int cur[BW];
  h[threadIdx.x] = 0;
  dg[threadIdx.x] = 0.f;
  __syncthreads();
  int e0 = bstart[c], e1 = bstart[c + 1];
  for (int e = e0 + threadIdx.x; e < e1; e += 256) {
    int2 p = pk1[e];
    int dl = p.x & 255;
    atomicAdd(&h[dl], 1);
    atomicAdd(&dg[dl], __int_as_float(p.y));
  }
  __syncthreads();
  int own = h[threadIdx.x];
  int hp = (own + 3) & ~3;           // padded count
  int v = hp;
  sc[threadIdx.x] = v;
  __syncthreads();
  for (int off = 1; off < 256; off <<= 1) {
    int o = threadIdx.x >= off ? sc[threadIdx.x - off] : 0;
    __syncthreads();
    v += o;
    sc[threadIdx.x] = v;
    __syncthreads();
  }
  int e0p = e0 + c * PADCAP;          // padded bucket base (capacity layout)
  int startp = e0p + v - hp;          // padded per-dst start
  cur[threadIdx.x] = startp;
  int i = dbase + threadIdx.x;
  if (i < n) dinv[i] = rsqrtf(dg[threadIdx.x] + 1.0f);   // self-loop +1
  if (i <= n) rowptr[i] = startp;                         // PADDED per-node CSR pointer
  if (threadIdx.x == 255) bendp[c] = e0p + v;             // padded bucket end
  __syncthreads();
  for (int e = e0 + threadIdx.x; e < e1; e += 256) {
    int2 p = pk1[e];
    int dl = p.x & 255;
    int slot = atomicAdd(&cur[dl], 1);
    pk2[slot] = make_int2((p.x >> 8) | (dl << 17), p.y);
  }
  // pad records: src = self (cache-hot), weight 0
  int npad = hp - own;
  for (int k = 0; k < npad; k++)
    pk2[startp + own + k] = make_int2(i | (threadIdx.x << 17), 0);
}

// ================= compute =================

// B fragment for MFMA 16x16x32: B[k = k0+j][col], bf16-RNE from fp32 W
__device__ __forceinline__ short8 bfrag(const float* __restrict__ W, int k0, int col) {
  short8 b;
#pragma unroll
  for (int j = 0; j < 8; j++) b[j] = (short)f2bf(W[(k0 + j) * DF + col]);
  return b;
}

// MFMA GEMM: xl' = bf16( (bf16(A) @ bf16(W)) * dinv_row )   (src-side dinv folded in)
__global__ __launch_bounds__(256) void gemm_init(const float* __restrict__ A,
                                                 const float* __restrict__ W,
                                                 const float* __restrict__ dinv,
                                                 u16* __restrict__ xl, int n, int tiles) {
  int lane = threadIdx.x & 63;
  int m = lane & 15, quad = lane >> 4;
  int wid = blockIdx.x * 4 + (threadIdx.x >> 6);
  int nw = gridDim.x * 4;
  short8 B0[4], B1[4];
#pragma unroll
  for (int ft = 0; ft < 4; ft++) {
    B0[ft] = bfrag(W, quad * 8, ft * 16 + m);
    B1[ft] = bfrag(W, 32 + quad * 8, ft * 16 + m);
  }
  for (int t = wid; t < tiles; t += nw) {
    int row0 = t * 16;
    int r = row0 + m;
    if (r >= n) r = n - 1;
    const float* ap = A + (size_t)r * DF + quad * 8;
    float4 u0 = *(const float4*)ap;
    float4 u1 = *(const float4*)(ap + 4);
    float4 u2 = *(const float4*)(ap + 32);
    float4 u3 = *(const float4*)(ap + 36);
    short8 a0, a1;
    a0[0]=(short)f2bf(u0.x); a0[1]=(short)f2bf(u0.y); a0[2]=(short)f2bf(u0.z); a0[3]=(short)f2bf(u0.w);
    a0[4]=(short)f2bf(u1.x); a0[5]=(short)f2bf(u1.y); a0[6]=(short)f2bf(u1.z); a0[7]=(short)f2bf(u1.w);
    a1[0]=(short)f2bf(u2.x); a1[1]=(short)f2bf(u2.y); a1[2]=(short)f2bf(u2.z); a1[3]=(short)f2bf(u2.w);
    a1[4]=(short)f2bf(u3.x); a1[5]=(short)f2bf(u3.y); a1[6]=(short)f2bf(u3.z); a1[7]=(short)f2bf(u3.w);
    f32x4 c[4];
#pragma unroll
    for (int ft = 0; ft < 4; ft++) c[ft] = (f32x4){0.f, 0.f, 0.f, 0.f};
#pragma unroll
    for (int ft = 0; ft < 4; ft++) {
      c[ft] = __builtin_amdgcn_mfma_f32_16x16x32_bf16(a0, B0[ft], c[ft], 0, 0, 0);
      c[ft] = __builtin_amdgcn_mfma_f32_16x16x32_bf16(a1, B1[ft], c[ft], 0, 0, 0);
    }
    float dd[4];
#pragma unroll
    for (int reg = 0; reg < 4; reg++) {
      int r2 = row0 + quad * 4 + reg;
      dd[reg] = (r2 < n) ? dinv[r2] : 0.f;
    }
#pragma unroll
    for (int ft = 0; ft < 4; ft++)
#pragma unroll
      for (int reg = 0; reg < 4; reg++) {
        int r2 = row0 + quad * 4 + reg;
        if (r2 < n)
          xl[(size_t)r2 * DF + ft * 16 + m] = f2bf(c[ft][reg] * dd[reg]);
      }
  }
}

// MFMA GEMM with BN+PReLU fused into A-load; same dinv-folded bf16 output
__global__ __launch_bounds__(256) void gemm_bn_init(const float* __restrict__ accin,
                                                    const float* __restrict__ stats,
                                                    const float* __restrict__ alpha_p,
                                                    const float* __restrict__ W,
                                                    const float* __restrict__ dinv,
                                                    u16* __restrict__ xl, int n, int tiles) {
  int lane = threadIdx.x & 63;
  int m = lane & 15, quad = lane >> 4;
  int wid = blockIdx.x * 4 + (threadIdx.x >> 6);
  int nw = gridDim.x * 4;
  short8 B0[4], B1[4];
#pragma unroll
  for (int ft = 0; ft < 4; ft++) {
    B0[ft] = bfrag(W, quad * 8, ft * 16 + m);
    B1[ft] = bfrag(W, 32 + quad * 8, ft * 16 + m);
  }
  float s0[8], t0[8], s1[8], t1[8];
#pragma unroll
  for (int j = 0; j < 8; j++) {
    s0[j] = stats[128 + quad * 8 + j];
    t0[j] = stats[192 + quad * 8 + j];
    s1[j] = stats[128 + 32 + quad * 8 + j];
    t1[j] = stats[192 + 32 + quad * 8 + j];
  }
  float al = alpha_p[0];
  for (int t = wid; t < tiles; t += nw) {
    int row0 = t * 16;
    int r = row0 + m;
    if (r >= n) r = n - 1;
    const float* ap = accin + (size_t)r * DF + quad * 8;
    float h0[8], h1[8];
#pragma unroll
    for (int j = 0; j < 8; j++) { h0[j] = ap[j]; h1[j] = ap[32 + j]; }
    short8 a0, a1;
#pragma unroll
    for (int j = 0; j < 8; j++) {
      float y0 = h0[j] * s0[j] + t0[j];
      y0 = (y0 >= 0.f) ? y0 : al * y0;
      a0[j] = (short)f2bf(y0);
      float y1 = h1[j] * s1[j] + t1[j];
      y1 = (y1 >= 0.f) ? y1 : al * y1;
      a1[j] = (short)f2bf(y1);
    }
    f32x4 c[4];
#pragma unroll
    for (int ft = 0; ft < 4; ft++) c[ft] = (f32x4){0.f, 0.f, 0.f, 0.f};
#pragma unroll
    for (int ft = 0; ft < 4; ft++) {
      c[ft] = __builtin_amdgcn_mfma_f32_16x16x32_bf16(a0, B0[ft], c[ft], 0, 0, 0);
      c[ft] = __builtin_amdgcn_mfma_f32_16x16x32_bf16(a1, B1[ft], c[ft], 0, 0, 0);
    }
    float dd[4];
#pragma unroll
    for (int reg = 0; reg < 4; reg++) {
      int r2 = row0 + quad * 4 + reg;
      dd[reg] = (r2 < n) ? dinv[r2] : 0.f;
    }
#pragma unroll
    for (int ft = 0; ft < 4; ft++)
#pragma unroll
      for (int reg = 0; reg < 4; reg++) {
        int r2 = row0 + quad * 4 + reg;
        if (r2 < n)
          xl[(size_t)r2 * DF + ft * 16 + m] = f2bf(c[ft][reg] * dd[reg]);
      }
  }
}

// owner-computes segmented aggregation, 4-edges-per-instruction layout:
// lane = (edge-slot g=lane>>4, feature-quad fb=(lane&15)*4). One ushort4 gather
// touches 4 independent src rows -> 4x memory-level parallelism per vmcnt slot
// with plain compiler scheduling (no asm). Rows padded to %4 edges by pass2 so
// 4-edge steps never straddle rows; flush does an 8-shuffle cross-group reduce.
__global__ __launch_bounds__(256) void edge_agg5(const int2* __restrict__ pk,
                                                 const int* __restrict__ rowptr,
                                                 const int* __restrict__ bendp,
                                                 const u16* __restrict__ xl,
                                                 const float* __restrict__ dinv,
                                                 const float* __restrict__ bias,
                                                 float* __restrict__ acc,
                                                 float* __restrict__ statp, int n) {
  int lane = threadIdx.x & 63;
  int wsub = threadIdx.x >> 6;
  int g = lane >> 4;                 // edge slot within a 4-edge step
  int fb = (lane & 15) * 4;          // feature base (4 features per lane)
  int ru = __builtin_amdgcn_readfirstlane((blockIdx.x * 4 + wsub) * 8);
  float ssumS = 0.f, ssqS = 0.f;                       // tail path (feature = lane)
  float sm0 = 0.f, sm1 = 0.f, sm2 = 0.f, sm3 = 0.f;    // fast path (features fb..fb+3, g==0)
  float sq0 = 0.f, sq1 = 0.f, sq2 = 0.f, sq3 = 0.f;
  bool fast = (ru < n) && (ru + 8 <= n);

  if (fast) {
    int gs = __builtin_amdgcn_readfirstlane(rowptr[ru]);
    int ge = (((ru + 8) & 255) == 0)
               ? __builtin_amdgcn_readfirstlane(bendp[ru >> 8])
               : __builtin_amdgcn_readfirstlane(rowptr[ru + 8]);
    int steps = (ge - gs) >> 2;
    const int2* __restrict__ pw = pk + gs;
    float bl0 = bias[fb], bl1 = bias[fb + 1], bl2 = bias[fb + 2], bl3 = bias[fb + 3];
    int row = ru, curdl = ru & 255, f = 0;
    float dv = dinv[row];
    float dvN = dinv[row + 1 < n ? row + 1 : n - 1];
    ushort4 sc4 = *(const ushort4*)(xl + ((size_t)row << 6) + fb);
    ushort4 sN4 = *(const ushort4*)(xl + ((size_t)(row + 1 < n ? row + 1 : n - 1) << 6) + fb);
    float a0 = (g == 0) ? bf2f(sc4.x) : 0.f;
    float a1 = (g == 0) ? bf2f(sc4.y) : 0.f;
    float a2 = (g == 0) ? bf2f(sc4.z) : 0.f;
    float a3 = (g == 0) ? bf2f(sc4.w) : 0.f;

#define FLUSH() do {                                                        \
    float r0_ = a0, r1_ = a1, r2_ = a2, r3_ = a3;                           \
    r0_ += __shfl_xor(r0_, 16); r1_ += __shfl_xor(r1_, 16);                 \
    r2_ += __shfl_xor(r2_, 16); r3_ += __shfl_xor(r3_, 16);                 \
    r0_ += __shfl_xor(r0_, 32); r1_ += __shfl_xor(r1_, 32);                 \
    r2_ += __shfl_xor(r2_, 32); r3_ += __shfl_xor(r3_, 32);                 \
    float v0_ = fmaf(r0_, dv, bl0), v1_ = fmaf(r1_, dv, bl1);               \
    float v2_ = fmaf(r2_, dv, bl2), v3_ = fmaf(r3_, dv, bl3);               \
    if (g == 0) {                                                           \
      float4 st_; st_.x = v0_; st_.y = v1_; st_.z = v2_; st_.w = v3_;       \
      *(float4*)(acc + ((size_t)row << 6) + fb) = st_;                      \
      sm0 += v0_; sm1 += v1_; sm2 += v2_; sm3 += v3_;                       \
      sq0 = fmaf(v0_, v0_, sq0); sq1 = fmaf(v1_, v1_, sq1);                 \
      sq2 = fmaf(v2_, v2_, sq2); sq3 = fmaf(v3_, v3_, sq3);                 \
    }                                                                       \
    row++; curdl++; f++;                                                    \
    dv = dvN; dvN = dinv[row + 1 < n ? row + 1 : n - 1];                    \
    a0 = (g == 0) ? bf2f(sN4.x) : 0.f; a1 = (g == 0) ? bf2f(sN4.y) : 0.f;   \
    a2 = (g == 0) ? bf2f(sN4.z) : 0.f; a3 = (g == 0) ? bf2f(sN4.w) : 0.f;   \
    sN4 = *(const ushort4*)(xl + ((size_t)(row + 1 < n ? row + 1 : n - 1) << 6) + fb); \
  } while (0)

    for (int s0 = 0; s0 < steps; s0 += 4) {
      int i0 = s0,     c0 = i0 < steps ? i0 : steps - 1;
      int i1 = s0 + 1, c1 = i1 < steps ? i1 : steps - 1;
      int i2 = s0 + 2, c2 = i2 < steps ? i2 : steps - 1;
      int i3 = s0 + 3, c3 = i3 < steps ? i3 : steps - 1;
      int2 rA = pw[c0 * 4 + g];
      int2 rB = pw[c1 * 4 + g];
      int2 rC = pw[c2 * 4 + g];
      int2 rD = pw[c3 * 4 + g];
      ushort4 gA = *(const ushort4*)(xl + ((size_t)(u32)(rA.x & 0x1FFFF) << 6) + fb);
      ushort4 gB = *(const ushort4*)(xl + ((size_t)(u32)(rB.x & 0x1FFFF) << 6) + fb);
      ushort4 gC = *(const ushort4*)(xl + ((size_t)(u32)(rC.x & 0x1FFFF) << 6) + fb);
      ushort4 gD = *(const ushort4*)(xl + ((size_t)(u32)(rD.x & 0x1FFFF) << 6) + fb);
      {
        int dl = __builtin_amdgcn_readfirstlane((rA.x >> 17) & 255);
        float w = (i0 < steps) ? __int_as_float(rA.y) : 0.f;
        while (dl != curdl) FLUSH();
        a0 = fmaf(w, bf2f(gA.x), a0); a1 = fmaf(w, bf2f(gA.y), a1);
        a2 = fmaf(w, bf2f(gA.z), a2); a3 = fmaf(w, bf2f(gA.w), a3);
      }
      {
        int dl = __builtin_amdgcn_readfirstlane((rB.x >> 17) & 255);
        float w = (i1 < steps) ? __int_as_float(rB.y) : 0.f;
        while (dl != curdl) FLUSH();
        a0 = fmaf(w, bf2f(gB.x), a0); a1 = fmaf(w, bf2f(gB.y), a1);
        a2 = fmaf(w, bf2f(gB.z), a2); a3 = fmaf(w, bf2f(gB.w), a3);
      }
      {
        int dl = __builtin_amdgcn_readfirstlane((rC.x >> 17) & 255);
        float w = (i2 < steps) ? __int_as_float(rC.y) : 0.f;
        while (dl != curdl) FLUSH();
        a0 = fmaf(w, bf2f(gC.x), a0); a1 = fmaf(w, bf2f(gC.y), a1);
        a2 = fmaf(w, bf2f(gC.z), a2); a3 = fmaf(w, bf2f(gC.w), a3);
      }
      {
        int dl = __builtin_amdgcn_readfirstlane((rD.x >> 17) & 255);
        float w = (i3 < steps) ? __int_as_float(rD.y) : 0.f;
        while (dl != curdl) FLUSH();
        a0 = fmaf(w, bf2f(gD.x), a0); a1 = fmaf(w, bf2f(gD.y), a1);
        a2 = fmaf(w, bf2f(gD.z), a2); a3 = fmaf(w, bf2f(gD.w), a3);
      }
    }
    while (f < 8) FLUSH();
#undef FLUSH
  } else if (ru < n) {
    // tail path (rare): per-row walk, feature = lane; pads (w=0) are harmless
    float bl = bias[lane];
    for (int row = ru; row < n; row++) {
      float aa = bf2f(xl[((size_t)row << 6) | lane]);
      int e0 = __builtin_amdgcn_readfirstlane(rowptr[row]);
      int e1 = __builtin_amdgcn_readfirstlane(rowptr[row + 1]);
      for (int e = e0; e < e1; e++) {
        int2 p = pk[e];
        float xv = bf2f(xl[((size_t)(p.x & 0x1FFFF) << 6) | lane]);
        aa = fmaf(__int_as_float(p.y), xv, aa);
      }
      float val = fmaf(aa, dinv[row], bl);
      acc[((size_t)row << 6) | lane] = val;
      ssumS += val;
      ssqS = fmaf(val, val, ssqS);
    }
  }

  __shared__ float ls[4][DF], lss[4][DF];
  ls[wsub][lane] = ssumS;            // zeros for fast-path / idle waves
  lss[wsub][lane] = ssqS;
  if (fast && g == 0) {              // same-wave later write wins (program order)
    ls[wsub][fb] = sm0; ls[wsub][fb + 1] = sm1; ls[wsub][fb + 2] = sm2; ls[wsub][fb + 3] = sm3;
    lss[wsub][fb] = sq0; lss[wsub][fb + 1] = sq1; lss[wsub][fb + 2] = sq2; lss[wsub][fb + 3] = sq3;
  }
  __syncthreads();
  if (threadIdx.x < DF) {
    int fi = threadIdx.x;
    float t1 = ls[0][fi] + ls[1][fi] + ls[2][fi] + ls[3][fi];
    float t2 = lss[0][fi] + lss[1][fi] + lss[2][fi] + lss[3][fi];
    int slot = (blockIdx.x & 63) * 128;   // 64-way spread kills same-line contention
    unsafeAtomicAdd(&statp[slot + fi], t1);
    unsafeAtomicAdd(&statp[slot + DF + fi], t2);
  }
}

__global__ void finalize_stats(const float* __restrict__ statp, float* __restrict__ stats,
                               const float* __restrict__ gamma,
                               const float* __restrict__ beta, int n) {
  int f = threadIdx.x;
  if (f >= DF) return;
  float s = 0.f, ss = 0.f;
#pragma unroll 4
  for (int c = 0; c < 64; c++) {
    s += statp[c * 128 + f];
    ss += statp[c * 128 + DF + f];
  }
  float mean = s / n;
  float var = ss / n - mean * mean;
  float rstd = rsqrtf(var + 1e-5f);
  float sc = gamma[f] * rstd;
  stats[128 + f] = sc;
  stats[192 + f] = beta[f] - mean * sc;
}

__global__ void bnapply(const float* __restrict__ acc, const float* __restrict__ stats,
                        const float* __restrict__ alpha_p, float* __restrict__ outb, int n) {
  int i = blockIdx.x * 4 + (threadIdx.x >> 6);
  if (i >= n) return;
  int f = threadIdx.x & 63;
  float y = acc[(size_t)i * DF + f] * stats[128 + f] + stats[192 + f];
  float a = alpha_p[0];
  y = (y >= 0.f) ? y : a * y;
  outb[(size_t)i * DF + f] = y;
}

extern "C" void kernel_launch(void* const* d_in, const int* in_sizes, int n_in,
                              void* d_out, int out_size, void* d_ws, size_t ws_size,
                              hipStream_t stream) {
  const float* x  = (const float*)d_in[0];
  const int* ei   = (const int*)d_in[1];
  const float* w  = (const float*)d_in[2];
  const float* W1 = (const float*)d_in[3];
  const float* b1 = (const float*)d_in[4];
  const float* g1 = (const float*)d_in[5];
  const float* be1= (const float*)d_in[6];
  const float* al1= (const float*)d_in[7];
  const float* W2 = (const float*)d_in[8];
  const float* b2 = (const float*)d_in[9];
  const float* g2 = (const float*)d_in[10];
  const float* be2= (const float*)d_in[11];
  const float* al2= (const float*)d_in[12];
  float* out = (float*)d_out;

  const int n = in_sizes[0] / DF;
  const int E = in_sizes[2];
  const size_t na = ((size_t)n + 255) & ~(size_t)255;
  const int NB = (n + BW - 1) >> BSH;
  const int nblk1 = (E + 1023) / 1024;
  const size_t ghsz = (((size_t)nblk1 * NB) + 3) & ~(size_t)3;
  const int tiles = (n + 15) / 16;
  const size_t pk2cap = (size_t)E + (size_t)NB * PADCAP + 64;

  // ---- workspace layout (4-byte units; int2 arrays 8B-aligned) ----
  float* wsf = (float*)d_ws;
  float* stats1 = wsf;                          // 256
  float* stats2 = stats1 + 256;                 // 256
  float* statp1 = stats2 + 256;                 // 8192 (64 spread copies x 128)
  float* statp2 = statp1 + 8192;                // 8192
  int*   btot   = (int*)(statp2 + 8192);        // 512
  int*   bstart = btot + 512;                   // 512 (NB+1 used)
  int*   bendp  = bstart + 512;                 // 512 (NB used)
  int*   rowptr = bendp + 512;                  // na + 4 (n+1 used)
  float* dinv   = (float*)(rowptr + na + 4);    // na
  int*   gh     = (int*)(dinv + na);            // ghsz
  int2*  pk2    = (int2*)(gh + ghsz);           // pk2cap records (8B each, padded CSR)
  int*   U      = (int*)(pk2 + pk2cap);         // overlay: pk1 (2E) | XL16+ACC
  int2*  pk1    = (int2*)U;
  u16*   XL16   = (u16*)U;                      // na*64 bf16 (after pass2)
  float* ACC    = (float*)(U + na * 32);        // na*64 fp32

  const int nb_nodes = (n + 3) / 4;
  const int nb_gemm  = 512;
  const int nb_agg   = (n + 31) / 32;

  hipMemsetAsync(stats1, 0, (512 + 16384) * sizeof(float), stream);

  // ---- CSR build (bucket sort, 8B records, padded per-node rowptr) ----
  prehist<<<nblk1, 256, 0, stream>>>(ei, gh, E, NB);
  scanA<<<NB, 256, 0, stream>>>(gh, btot, nblk1, NB);
  scanB<<<1, 256, 0, stream>>>(btot, bstart, rowptr, NB, n, E);
  pass1<<<nblk1, 256, 0, stream>>>(ei, w, gh, bstart, pk1, E, NB);
  pass2<<<NB, 256, 0, stream>>>(pk1, bstart, pk2, dinv, rowptr, bendp, n);

  // ---- layer 1 ----
  gemm_init<<<nb_gemm, 256, 0, stream>>>(x, W1, dinv, XL16, n, tiles);
  edge_agg5<<<nb_agg, 256, 0, stream>>>(pk2, rowptr, bendp, XL16, dinv, b1, ACC, statp1, n);
  finalize_stats<<<1, 64, 0, stream>>>(statp1, stats1, g1, be1, n);

  // ---- layer 2 ----
  gemm_bn_init<<<nb_gemm, 256, 0, stream>>>(ACC, stats1, al1, W2, dinv, XL16, n, tiles);
  edge_agg5<<<nb_agg, 256, 0, stream>>>(pk2, rowptr, bendp, XL16, dinv, b2, ACC, statp2, n);
  finalize_stats<<<1, 64, 0, stream>>>(statp2, stats2, g2, be2, n);
  bnapply<<<nb_nodes, 256, 0, stream>>>(ACC, stats2, al2, out, n);
}

// Round 5
// 330.717 us; speedup vs baseline: 1.2930x; 1.0012x over previous
//
#include <hip/hip_runtime.h>

#define DF 64
#define BSH 8              // bucket = dst >> 8  (256 dst per bucket)
#define BW  256
#define PADCAP 768         // per-bucket extra pk2 capacity: 256 dst * 3 pad max

typedef unsigned short u16;
typedef unsigned int u32;
typedef __attribute__((ext_vector_type(8))) short short8;
typedef __attribute__((ext_vector_type(4))) float f32x4;

__device__ __forceinline__ float bf2f(u16 u) { return __uint_as_float(((u32)u) << 16); }
__device__ __forceinline__ u16 f2bf(float f) {
  u32 v = __float_as_uint(f);
  return (u16)((v + 0x7FFFu + ((v >> 16) & 1u)) >> 16);
}

// ============== bucket-sort CSR build (atomic-free globals) ==============

__global__ __launch_bounds__(256) void prehist(const int* __restrict__ ei,
                                               int* __restrict__ gh, int E, int NB) {
  __shared__ int lh[512];
  for (int t = threadIdx.x; t < NB; t += 256) lh[t] = 0;
  __syncthreads();
  int e0 = blockIdx.x * 1024;
#pragma unroll
  for (int j = 0; j < 4; j++) {
    int e = e0 + j * 256 + threadIdx.x;
    if (e < E) atomicAdd(&lh[ei[E + e] >> BSH], 1);
  }
  __syncthreads();
  for (int t = threadIdx.x; t < NB; t += 256)
    gh[(size_t)blockIdx.x * NB + t] = lh[t];
}

__global__ __launch_bounds__(256) void scanA(int* __restrict__ gh, int* __restrict__ btot,
                                             int nblk, int NB) {
  int c = blockIdx.x;
  __shared__ int sc[256];
  int carry = 0;
  for (int b0 = 0; b0 < nblk; b0 += 256) {
    int b = b0 + threadIdx.x;
    int orig = (b < nblk) ? gh[(size_t)b * NB + c] : 0;
    int v = orig;
    sc[threadIdx.x] = v;
    __syncthreads();
    for (int off = 1; off < 256; off <<= 1) {
      int o = threadIdx.x >= off ? sc[threadIdx.x - off] : 0;
      __syncthreads();
      v += o;
      sc[threadIdx.x] = v;
      __syncthreads();
    }
    int ctot = sc[255];
    if (b < nblk) gh[(size_t)b * NB + c] = carry + v - orig;
    carry += ctot;
    __syncthreads();
  }
  if (threadIdx.x == 0) btot[c] = carry;
}

__global__ __launch_bounds__(256) void scanB(const int* __restrict__ btot,
                                             int* __restrict__ bstart,
                                             int* __restrict__ rowptr, int NB, int n, int E) {
  __shared__ int sc[256];
  int base = threadIdx.x * 4;
  int c[4], s = 0;
#pragma unroll
  for (int j = 0; j < 4; j++) {
    int idx = base + j;
    c[j] = idx < NB ? btot[idx] : 0;
    s += c[j];
  }
  int v = s;
  sc[threadIdx.x] = v;
  __syncthreads();
  for (int off = 1; off < 256; off <<= 1) {
    int o = threadIdx.x >= off ? sc[threadIdx.x - off] : 0;
    __syncthreads();
    v += o;
    sc[threadIdx.x] = v;
    __syncthreads();
  }
  int run = v - s;
#pragma unroll
  for (int j = 0; j < 4; j++) {
    int idx = base + j;
    if (idx <= NB) bstart[idx] = run;
    run += c[j];
  }
}

// bin edges into dst-buckets; 8B records {dl | src<<8, w_fp32}
__global__ __launch_bounds__(256) void pass1(const int* __restrict__ ei,
                                             const float* __restrict__ w,
                                             const int* __restrict__ gh,
                                             const int* __restrict__ bstart,
                                             int2* __restrict__ pk1, int E, int NB) {
  __shared__ int lh[512];
  __shared__ int lbase[512];
  for (int t = threadIdx.x; t < NB; t += 256) lh[t] = 0;
  __syncthreads();
  int e0 = blockIdx.x * 1024;
  int s[4], d[4], r[4];
  float wv[4];
#pragma unroll
  for (int j = 0; j < 4; j++) {
    int e = e0 + j * 256 + threadIdx.x;
    if (e < E) {
      s[j] = ei[e];
      d[j] = ei[E + e];
      wv[j] = w[e];
      r[j] = atomicAdd(&lh[d[j] >> BSH], 1);
    }
  }
  __syncthreads();
  for (int t = threadIdx.x; t < NB; t += 256)
    lbase[t] = bstart[t] + gh[(size_t)blockIdx.x * NB + t];
  __syncthreads();
#pragma unroll
  for (int j = 0; j < 4; j++) {
    int e = e0 + j * 256 + threadIdx.x;
    if (e < E)
      pk1[lbase[d[j] >> BSH] + r[j]] =
          make_int2((d[j] & 255) | (s[j] << 8), __float_as_int(wv[j]));
  }
}

// per-bucket counting sort (LDS) -> pk2 {src | dl<<17, w_fp32}; per-row counts padded
// to a multiple of 4 with {src=self, w=0} records so 4-edge steps never straddle rows.
// Emits dinv, PADDED per-node rowptr, and per-bucket padded end (bendp).
__global__ __launch_bounds__(256) void pass2(const int2* __restrict__ pk1,
                                             const int* __restrict__ bstart,
                                             int2* __restrict__ pk2,
                                             float* __restrict__ dinv,
                                             int* __restrict__ rowptr,
                                             int* __restrict__ bendp, int n) {
  int c = blockIdx.x;
  int dbase = c << BSH;
  __shared__ int h[BW];
  __shared__ float dg[BW];
  __shared__ int sc[BW];
  __shared__ int cur[BW];
  h[threadIdx.x] = 0;
  dg[threadIdx.x] = 0.f;
  __syncthreads();
  int e0 = bstart[c], e1 = bstart[c + 1];
  for (int e = e0 + threadIdx.x; e < e1; e += 256) {
    int2 p = pk1[e];
    int dl = p.x & 255;
    atomicAdd(&h[dl], 1);
    atomicAdd(&dg[dl], __int_as_float(p.y));
  }
  __syncthreads();
  int own = h[threadIdx.x];
  int hp = (own + 3) & ~3;           // padded count
  int v = hp;
  sc[threadIdx.x] = v;
  __syncthreads();
  for (int off = 1; off < 256; off <<= 1) {
    int o = threadIdx.x >= off ? sc[threadIdx.x - off] : 0;
    __syncthreads();
    v += o;
    sc[threadIdx.x] = v;
    __syncthreads();
  }
  int e0p = e0 + c * PADCAP;          // padded bucket base (capacity layout)
  int startp = e0p + v - hp;          // padded per-dst start
  cur[threadIdx.x] = startp;
  int i = dbase + threadIdx.x;
  if (i < n) dinv[i] = rsqrtf(dg[threadIdx.x] + 1.0f);   // self-loop +1
  if (i <= n) rowptr[i] = startp;                         // PADDED per-node CSR pointer
  if (threadIdx.x == 255) bendp[c] = e0p + v;             // padded bucket end
  __syncthreads();
  for (int e = e0 + threadIdx.x; e < e1; e += 256) {
    int2 p = pk1[e];
    int dl = p.x & 255;
    int slot = atomicAdd(&cur[dl], 1);
    pk2[slot] = make_int2((p.x >> 8) | (dl << 17), p.y);
  }
  // pad records: src = self (cache-hot), weight 0
  int npad = hp - own;
  for (int k = 0; k < npad; k++)
    pk2[startp + own + k] = make_int2(i | (threadIdx.x << 17), 0);
}

// ================= compute =================

// B fragment for MFMA 16x16x32: B[k = k0+j][col], bf16-RNE from fp32 W
__device__ __forceinline__ short8 bfrag(const float* __restrict__ W, int k0, int col) {
  short8 b;
#pragma unroll
  for (int j = 0; j < 8; j++) b[j] = (short)f2bf(W[(k0 + j) * DF + col]);
  return b;
}

// MFMA GEMM: xl' = bf16( (bf16(A) @ bf16(W)) * dinv_row )   (src-side dinv folded in)
__global__ __launch_bounds__(256) void gemm_init(const float* __restrict__ A,
                                                 const float* __restrict__ W,
                                                 const float* __restrict__ dinv,
                                                 u16* __restrict__ xl, int n, int tiles) {
  int lane = threadIdx.x & 63;
  int m = lane & 15, quad = lane >> 4;
  int wid = blockIdx.x * 4 + (threadIdx.x >> 6);
  int nw = gridDim.x * 4;
  short8 B0[4], B1[4];
#pragma unroll
  for (int ft = 0; ft < 4; ft++) {
    B0[ft] = bfrag(W, quad * 8, ft * 16 + m);
    B1[ft] = bfrag(W, 32 + quad * 8, ft * 16 + m);
  }
  for (int t = wid; t < tiles; t += nw) {
    int row0 = t * 16;
    int r = row0 + m;
    if (r >= n) r = n - 1;
    const float* ap = A + (size_t)r * DF + quad * 8;
    float4 u0 = *(const float4*)ap;
    float4 u1 = *(const float4*)(ap + 4);
    float4 u2 = *(const float4*)(ap + 32);
    float4 u3 = *(const float4*)(ap + 36);
    short8 a0, a1;
    a0[0]=(short)f2bf(u0.x); a0[1]=(short)f2bf(u0.y); a0[2]=(short)f2bf(u0.z); a0[3]=(short)f2bf(u0.w);
    a0[4]=(short)f2bf(u1.x); a0[5]=(short)f2bf(u1.y); a0[6]=(short)f2bf(u1.z); a0[7]=(short)f2bf(u1.w);
    a1[0]=(short)f2bf(u2.x); a1[1]=(short)f2bf(u2.y); a1[2]=(short)f2bf(u2.z); a1[3]=(short)f2bf(u2.w);
    a1[4]=(short)f2bf(u3.x); a1[5]=(short)f2bf(u3.y); a1[6]=(short)f2bf(u3.z); a1[7]=(short)f2bf(u3.w);
    f32x4 c[4];
#pragma unroll
    for (int ft = 0; ft < 4; ft++) c[ft] = (f32x4){0.f, 0.f, 0.f, 0.f};
#pragma unroll
    for (int ft = 0; ft < 4; ft++) {
      c[ft] = __builtin_amdgcn_mfma_f32_16x16x32_bf16(a0, B0[ft], c[ft], 0, 0, 0);
      c[ft] = __builtin_amdgcn_mfma_f32_16x16x32_bf16(a1, B1[ft], c[ft], 0, 0, 0);
    }
    float dd[4];
#pragma unroll
    for (int reg = 0; reg < 4; reg++) {
      int r2 = row0 + quad * 4 + reg;
      dd[reg] = (r2 < n) ? dinv[r2] : 0.f;
    }
#pragma unroll
    for (int ft = 0; ft < 4; ft++)
#pragma unroll
      for (int reg = 0; reg < 4; reg++) {
        int r2 = row0 + quad * 4 + reg;
        if (r2 < n)
          xl[(size_t)r2 * DF + ft * 16 + m] = f2bf(c[ft][reg] * dd[reg]);
      }
  }
}

// MFMA GEMM with BN+PReLU fused into A-load; same dinv-folded bf16 output
__global__ __launch_bounds__(256) void gemm_bn_init(const float* __restrict__ accin,
                                                    const float* __restrict__ stats,
                                                    const float* __restrict__ alpha_p,
                                                    const float* __restrict__ W,
                                                    const float* __restrict__ dinv,
                                                    u16* __restrict__ xl, int n, int tiles) {
  int lane = threadIdx.x & 63;
  int m = lane & 15, quad = lane >> 4;
  int wid = blockIdx.x * 4 + (threadIdx.x >> 6);
  int nw = gridDim.x * 4;
  short8 B0[4], B1[4];
#pragma unroll
  for (int ft = 0; ft < 4; ft++) {
    B0[ft] = bfrag(W, quad * 8, ft * 16 + m);
    B1[ft] = bfrag(W, 32 + quad * 8, ft * 16 + m);
  }
  float s0[8], t0[8], s1[8], t1[8];
#pragma unroll
  for (int j = 0; j < 8; j++) {
    s0[j] = stats[128 + quad * 8 + j];
    t0[j] = stats[192 + quad * 8 + j];
    s1[j] = stats[128 + 32 + quad * 8 + j];
    t1[j] = stats[192 + 32 + quad * 8 + j];
  }
  float al = alpha_p[0];
  for (int t = wid; t < tiles; t += nw) {
    int row0 = t * 16;
    int r = row0 + m;
    if (r >= n) r = n - 1;
    const float* ap = accin + (size_t)r * DF + quad * 8;
    float h0[8], h1[8];
#pragma unroll
    for (int j = 0; j < 8; j++) { h0[j] = ap[j]; h1[j] = ap[32 + j]; }
    short8 a0, a1;
#pragma unroll
    for (int j = 0; j < 8; j++) {
      float y0 = h0[j] * s0[j] + t0[j];
      y0 = (y0 >= 0.f) ? y0 : al * y0;
      a0[j] = (short)f2bf(y0);
      float y1 = h1[j] * s1[j] + t1[j];
      y1 = (y1 >= 0.f) ? y1 : al * y1;
      a1[j] = (short)f2bf(y1);
    }
    f32x4 c[4];
#pragma unroll
    for (int ft = 0; ft < 4; ft++) c[ft] = (f32x4){0.f, 0.f, 0.f, 0.f};
#pragma unroll
    for (int ft = 0; ft < 4; ft++) {
      c[ft] = __builtin_amdgcn_mfma_f32_16x16x32_bf16(a0, B0[ft], c[ft], 0, 0, 0);
      c[ft] = __builtin_amdgcn_mfma_f32_16x16x32_bf16(a1, B1[ft], c[ft], 0, 0, 0);
    }
    float dd[4];
#pragma unroll
    for (int reg = 0; reg < 4; reg++) {
      int r2 = row0 + quad * 4 + reg;
      dd[reg] = (r2 < n) ? dinv[r2] : 0.f;
    }
#pragma unroll
    for (int ft = 0; ft < 4; ft++)
#pragma unroll
      for (int reg = 0; reg < 4; reg++) {
        int r2 = row0 + quad * 4 + reg;
        if (r2 < n)
          xl[(size_t)r2 * DF + ft * 16 + m] = f2bf(c[ft][reg] * dd[reg]);
      }
  }
}

// owner-computes segmented aggregation, per-row counted inner loop:
// wave owns 4 rows; per row, steps = padded_edges/4 (exact, pass2 pads %4).
// Inner loop: 4 records + 4 four-line ushort4 gathers + 16 FMA — no row-boundary
// logic, no stores, no data-dependent control flow -> loads of block s+1 are free
// to issue past block s's FMA chain. Flush (shuffle-reduce + store + stats) once
// per row, outside the loop.
__global__ __launch_bounds__(256) void edge_agg6(const int2* __restrict__ pk,
                                                 const int* __restrict__ rowptr,
                                                 const int* __restrict__ bendp,
                                                 const u16* __restrict__ xl,
                                                 const float* __restrict__ dinv,
                                                 const float* __restrict__ bias,
                                                 float* __restrict__ acc,
                                                 float* __restrict__ statp, int n) {
  int lane = threadIdx.x & 63;
  int wsub = threadIdx.x >> 6;
  int g = lane >> 4;                 // edge slot within a 4-edge step
  int fb = (lane & 15) * 4;          // feature base (4 features per lane)
  int ru = __builtin_amdgcn_readfirstlane((blockIdx.x * 4 + wsub) * 4);
  float bl0 = bias[fb], bl1 = bias[fb + 1], bl2 = bias[fb + 2], bl3 = bias[fb + 3];
  float sm0 = 0.f, sm1 = 0.f, sm2 = 0.f, sm3 = 0.f;
  float sq0 = 0.f, sq1 = 0.f, sq2 = 0.f, sq3 = 0.f;

  if (ru < n) {
    int rmax = min(ru + 4, n);
    for (int row = ru; row < rmax; row++) {
      int gs = __builtin_amdgcn_readfirstlane(rowptr[row]);
      int ge = (((row + 1) & 255) == 0)
                 ? __builtin_amdgcn_readfirstlane(bendp[row >> 8])
                 : __builtin_amdgcn_readfirstlane(rowptr[row + 1]);
      int steps = (ge - gs) >> 2;
      const int2* __restrict__ pw = pk + gs;
      float dv = dinv[row];
      ushort4 s4 = *(const ushort4*)(xl + ((size_t)row << 6) + fb);
      float a0 = (g == 0) ? bf2f(s4.x) : 0.f;   // self-loop: xl' already has dinv_d
      float a1 = (g == 0) ? bf2f(s4.y) : 0.f;
      float a2 = (g == 0) ? bf2f(s4.z) : 0.f;
      float a3 = (g == 0) ? bf2f(s4.w) : 0.f;

      for (int s0 = 0; s0 < steps; s0 += 4) {
        int i1 = s0 + 1, i2 = s0 + 2, i3 = s0 + 3;
        int c1 = i1 < steps ? i1 : steps - 1;
        int c2 = i2 < steps ? i2 : steps - 1;
        int c3 = i3 < steps ? i3 : steps - 1;
        int2 rA = pw[s0 * 4 + g];
        int2 rB = pw[c1 * 4 + g];
        int2 rC = pw[c2 * 4 + g];
        int2 rD = pw[c3 * 4 + g];
        ushort4 gA = *(const ushort4*)(xl + ((size_t)(u32)(rA.x & 0x1FFFF) << 6) + fb);
        ushort4 gB = *(const ushort4*)(xl + ((size_t)(u32)(rB.x & 0x1FFFF) << 6) + fb);
        ushort4 gC = *(const ushort4*)(xl + ((size_t)(u32)(rC.x & 0x1FFFF) << 6) + fb);
        ushort4 gD = *(const ushort4*)(xl + ((size_t)(u32)(rD.x & 0x1FFFF) << 6) + fb);
        float wA = __int_as_float(rA.y);                       // s0 always < steps
        float wB = (i1 < steps) ? __int_as_float(rB.y) : 0.f;  // clamped dupes: w=0
        float wC = (i2 < steps) ? __int_as_float(rC.y) : 0.f;
        float wD = (i3 < steps) ? __int_as_float(rD.y) : 0.f;
        a0 = fmaf(wA, bf2f(gA.x), a0); a1 = fmaf(wA, bf2f(gA.y), a1);
        a2 = fmaf(wA, bf2f(gA.z), a2); a3 = fmaf(wA, bf2f(gA.w), a3);
        a0 = fmaf(wB, bf2f(gB.x), a0); a1 = fmaf(wB, bf2f(gB.y), a1);
        a2 = fmaf(wB, bf2f(gB.z), a2); a3 = fmaf(wB, bf2f(gB.w), a3);
        a0 = fmaf(wC, bf2f(gC.x), a0); a1 = fmaf(wC, bf2f(gC.y), a1);
        a2 = fmaf(wC, bf2f(gC.z), a2); a3 = fmaf(wC, bf2f(gC.w), a3);
        a0 = fmaf(wD, bf2f(gD.x), a0); a1 = fmaf(wD, bf2f(gD.y), a1);
        a2 = fmaf(wD, bf2f(gD.z), a2); a3 = fmaf(wD, bf2f(gD.w), a3);
      }

      // flush: cross-group reduce (4 groups -> 2 shuffle rounds)
      float r0 = a0, r1 = a1, r2 = a2, r3 = a3;
      r0 += __shfl_xor(r0, 16); r1 += __shfl_xor(r1, 16);
      r2 += __shfl_xor(r2, 16); r3 += __shfl_xor(r3, 16);
      r0 += __shfl_xor(r0, 32); r1 += __shfl_xor(r1, 32);
      r2 += __shfl_xor(r2, 32); r3 += __shfl_xor(r3, 32);
      float v0 = fmaf(r0, dv, bl0), v1 = fmaf(r1, dv, bl1);
      float v2 = fmaf(r2, dv, bl2), v3 = fmaf(r3, dv, bl3);
      if (g == 0) {
        float4 st; st.x = v0; st.y = v1; st.z = v2; st.w = v3;
        *(float4*)(acc + ((size_t)row << 6) + fb) = st;
        sm0 += v0; sm1 += v1; sm2 += v2; sm3 += v3;
        sq0 = fmaf(v0, v0, sq0); sq1 = fmaf(v1, v1, sq1);
        sq2 = fmaf(v2, v2, sq2); sq3 = fmaf(v3, v3, sq3);
      }
    }
  }

  __shared__ float ls[4][DF], lss[4][DF];
  if (g == 0) {                      // 16 lanes cover all 64 features via fb quads
    float4 t1; t1.x = sm0; t1.y = sm1; t1.z = sm2; t1.w = sm3;
    float4 t2; t2.x = sq0; t2.y = sq1; t2.z = sq2; t2.w = sq3;
    *(float4*)&ls[wsub][fb] = t1;
    *(float4*)&lss[wsub][fb] = t2;
  }
  __syncthreads();
  if (threadIdx.x < DF) {
    int fi = threadIdx.x;
    float t1 = ls[0][fi] + ls[1][fi] + ls[2][fi] + ls[3][fi];
    float t2 = lss[0][fi] + lss[1][fi] + lss[2][fi] + lss[3][fi];
    int slot = (blockIdx.x & 63) * 128;   // 64-way spread kills same-line contention
    unsafeAtomicAdd(&statp[slot + fi], t1);
    unsafeAtomicAdd(&statp[slot + DF + fi], t2);
  }
}

__global__ void finalize_stats(const float* __restrict__ statp, float* __restrict__ stats,
                               const float* __restrict__ gamma,
                               const float* __restrict__ beta, int n) {
  int f = threadIdx.x;
  if (f >= DF) return;
  float s = 0.f, ss = 0.f;
#pragma unroll 4
  for (int c = 0; c < 64; c++) {
    s += statp[c * 128 + f];
    ss += statp[c * 128 + DF + f];
  }
  float mean = s / n;
  float var = ss / n - mean * mean;
  float rstd = rsqrtf(var + 1e-5f);
  float sc = gamma[f] * rstd;
  stats[128 + f] = sc;
  stats[192 + f] = beta[f] - mean * sc;
}

__global__ void bnapply(const float* __restrict__ acc, const float* __restrict__ stats,
                        const float* __restrict__ alpha_p, float* __restrict__ outb, int n) {
  int i = blockIdx.x * 4 + (threadIdx.x >> 6);
  if (i >= n) return;
  int f = threadIdx.x & 63;
  float y = acc[(size_t)i * DF + f] * stats[128 + f] + stats[192 + f];
  float a = alpha_p[0];
  y = (y >= 0.f) ? y : a * y;
  outb[(size_t)i * DF + f] = y;
}

extern "C" void kernel_launch(void* const* d_in, const int* in_sizes, int n_in,
                              void* d_out, int out_size, void* d_ws, size_t ws_size,
                              hipStream_t stream) {
  const float* x  = (const float*)d_in[0];
  const int* ei   = (const int*)d_in[1];
  const float* w  = (const float*)d_in[2];
  const float* W1 = (const float*)d_in[3];
  const float* b1 = (const float*)d_in[4];
  const float* g1 = (const float*)d_in[5];
  const float* be1= (const float*)d_in[6];
  const float* al1= (const float*)d_in[7];
  const float* W2 = (const float*)d_in[8];
  const float* b2 = (const float*)d_in[9];
  const float* g2 = (const float*)d_in[10];
  const float* be2= (const float*)d_in[11];
  const float* al2= (const float*)d_in[12];
  float* out = (float*)d_out;

  const int n = in_sizes[0] / DF;
  const int E = in_sizes[2];
  const size_t na = ((size_t)n + 255) & ~(size_t)255;
  const int NB = (n + BW - 1) >> BSH;
  const int nblk1 = (E + 1023) / 1024;
  const size_t ghsz = (((size_t)nblk1 * NB) + 3) & ~(size_t)3;
  const int tiles = (n + 15) / 16;
  const size_t pk2cap = (size_t)E + (size_t)NB * PADCAP + 64;

  // ---- workspace layout (4-byte units; int2 arrays 8B-aligned) ----
  float* wsf = (float*)d_ws;
  float* stats1 = wsf;                          // 256
  float* stats2 = stats1 + 256;                 // 256
  float* statp1 = stats2 + 256;                 // 8192 (64 spread copies x 128)
  float* statp2 = statp1 + 8192;                // 8192
  int*   btot   = (int*)(statp2 + 8192);        // 512
  int*   bstart = btot + 512;                   // 512 (NB+1 used)
  int*   bendp  = bstart + 512;                 // 512 (NB used)
  int*   rowptr = bendp + 512;                  // na + 4 (n+1 used)
  float* dinv   = (float*)(rowptr + na + 4);    // na
  int*   gh     = (int*)(dinv + na);            // ghsz
  int2*  pk2    = (int2*)(gh + ghsz);           // pk2cap records (8B each, padded CSR)
  int*   U      = (int*)(pk2 + pk2cap);         // overlay: pk1 (2E) | XL16+ACC
  int2*  pk1    = (int2*)U;
  u16*   XL16   = (u16*)U;                      // na*64 bf16 (after pass2)
  float* ACC    = (float*)(U + na * 32);        // na*64 fp32

  const int nb_nodes = (n + 3) / 4;
  const int nb_gemm  = 512;
  const int nb_agg   = (n + 15) / 16;           // wave = 4 rows, block = 16 rows

  hipMemsetAsync(stats1, 0, (512 + 16384) * sizeof(float), stream);

  // ---- CSR build (bucket sort, 8B records, padded per-node rowptr) ----
  prehist<<<nblk1, 256, 0, stream>>>(ei, gh, E, NB);
  scanA<<<NB, 256, 0, stream>>>(gh, btot, nblk1, NB);
  scanB<<<1, 256, 0, stream>>>(btot, bstart, rowptr, NB, n, E);
  pass1<<<nblk1, 256, 0, stream>>>(ei, w, gh, bstart, pk1, E, NB);
  pass2<<<NB, 256, 0, stream>>>(pk1, bstart, pk2, dinv, rowptr, bendp, n);

  // ---- layer 1 ----
  gemm_init<<<nb_gemm, 256, 0, stream>>>(x, W1, dinv, XL16, n, tiles);
  edge_agg6<<<nb_agg, 256, 0, stream>>>(pk2, rowptr, bendp, XL16, dinv, b1, ACC, statp1, n);
  finalize_stats<<<1, 64, 0, stream>>>(statp1, stats1, g1, be1, n);

  // ---- layer 2 ----
  gemm_bn_init<<<nb_gemm, 256, 0, stream>>>(ACC, stats1, al1, W2, dinv, XL16, n, tiles);
  edge_agg6<<<nb_agg, 256, 0, stream>>>(pk2, rowptr, bendp, XL16, dinv, b2, ACC, statp2, n);
  finalize_stats<<<1, 64, 0, stream>>>(statp2, stats2, g2, be2, n);
  bnapply<<<nb_nodes, 256, 0, stream>>>(ACC, stats2, al2, out, n);
}